// Round 6
// baseline (4279.554 us; speedup 1.0000x reference)
//
#include <hip/hip_runtime.h>

#define B_SZ 64
#define N_SZ 1024
#define C1   64
#define C2   128
#define C3   256
#define H_SZ 256

// ------------------------------------------------------------------
// Spectral norm of A (256x256) via repeated squaring of B = A^T A.
// ------------------------------------------------------------------
__global__ void k_btb(const float* __restrict__ A, float* __restrict__ B0) {
  int i = blockIdx.x;
  int j = threadIdx.x;
  float acc = 0.f;
  for (int k = 0; k < 256; ++k)
    acc = fmaf(A[k * 256 + i], A[k * 256 + j], acc);
  B0[i * 256 + j] = acc;
}

__global__ void k_bsq(const float* __restrict__ Bin, float* __restrict__ Bout) {
  __shared__ float diag[256];
  int i = blockIdx.x, j = threadIdx.x;
  diag[j] = Bin[j * 256 + j];
  __syncthreads();
  float tr = 0.f;
  for (int k = 0; k < 256; ++k) tr += diag[k];
  float inv = 1.0f / tr;
  float acc = 0.f;
  for (int k = 0; k < 256; ++k)
    acc = fmaf(Bin[i * 256 + k], Bin[k * 256 + j], acc);
  Bout[i * 256 + j] = acc * inv * inv;
}

__global__ void k_sfin(const float* __restrict__ Bf, const float* __restrict__ B0,
                       float* __restrict__ sinv) {
  __shared__ float v[256], w[256];
  __shared__ float red[256];
  __shared__ int redi[256];
  int t = threadIdx.x;
  red[t] = Bf[t * 256 + t];
  redi[t] = t;
  __syncthreads();
  for (int s = 128; s > 0; s >>= 1) {
    if (t < s) {
      if (red[t + s] > red[t]) { red[t] = red[t + s]; redi[t] = redi[t + s]; }
    }
    __syncthreads();
  }
  int jmax = redi[0];
  __syncthreads();
  v[t] = Bf[t * 256 + jmax];
  __syncthreads();
  float acc = 0.f;
  for (int k = 0; k < 256; ++k) acc = fmaf(B0[t * 256 + k], v[k], acc);
  w[t] = acc;
  __syncthreads();
  red[t] = v[t] * w[t];
  __syncthreads();
  for (int s = 128; s > 0; s >>= 1) { if (t < s) red[t] += red[t + s]; __syncthreads(); }
  float num = red[0];
  __syncthreads();
  red[t] = v[t] * v[t];
  __syncthreads();
  for (int s = 128; s > 0; s >>= 1) { if (t < s) red[t] += red[t + s]; __syncthreads(); }
  if (t == 0) {
    float lam = num / red[0];
    float sg = sqrtf(lam);
    *sinv = 1.0f / (sg + 1e-5f);
  }
}

// ------------------------------------------------------------------
// Layer 1: y1 = w1 @ x + b1   (K = 3)
// ------------------------------------------------------------------
__global__ void k_conv1(const float* __restrict__ x, const float* __restrict__ w,
                        const float* __restrict__ bias, float* __restrict__ y) {
  int b = blockIdx.x >> 2;
  int n = ((blockIdx.x & 3) << 8) + threadIdx.x;
  const float* xb = x + (size_t)b * 3 * N_SZ;
  float x0 = xb[n], x1 = xb[N_SZ + n], x2 = xb[2 * N_SZ + n];
  float* yb = y + (size_t)b * C1 * N_SZ;
#pragma unroll 4
  for (int o = 0; o < C1; ++o) {
    float r = fmaf(w[o * 3 + 0], x0,
              fmaf(w[o * 3 + 1], x1,
              fmaf(w[o * 3 + 2], x2, bias[o])));
    yb[(size_t)o * N_SZ + n] = r;
  }
}

// ------------------------------------------------------------------
// Per-channel BN stats over (B, N) -> affine coef.
// ------------------------------------------------------------------
__global__ void k_stats(const float* __restrict__ y, int C,
                        const float* __restrict__ g, const float* __restrict__ be,
                        float* __restrict__ coef) {
  int c = blockIdx.x;
  int t = threadIdx.x;
  float s1 = 0.f, s2 = 0.f;
  for (int b = 0; b < B_SZ; ++b) {
    const float4* p = (const float4*)(y + ((size_t)b * C + c) * N_SZ);
    float4 v = p[t];
    s1 += v.x + v.y + v.z + v.w;
    s2 += v.x * v.x + v.y * v.y + v.z * v.z + v.w * v.w;
  }
  __shared__ float r1[256], r2[256];
  r1[t] = s1; r2[t] = s2;
  __syncthreads();
  for (int s = 128; s > 0; s >>= 1) {
    if (t < s) { r1[t] += r1[t + s]; r2[t] += r2[t + s]; }
    __syncthreads();
  }
  if (t == 0) {
    const float M = (float)(B_SZ * N_SZ);
    float mu = r1[0] / M;
    float var = r2[0] / M - mu * mu;
    float sc = g[c] * rsqrtf(var + 1e-5f);
    coef[c] = sc;
    coef[C + c] = be[c] - mu * sc;
  }
}

// ==================================================================
// GEMM kernels v2: 128(M) x 256(N) tile, 256 threads, 8x16/thread
// (128 fma per 6 LDS b128 reads — at the CU's VALU:LDS balance).
// Register double-buffered staging, ONE raw lgkm-barrier per k-tile
// (no vmcnt(0) drain at barriers; global loads hide under compute).
// ==================================================================

#define GEMM_COMPUTE(ATc, BTc)                                        \
  _Pragma("unroll") for (int kk = 0; kk < 8; ++kk) {                  \
    float av[2][4], bv[4][4];                                         \
    *(float4*)av[0] = *(const float4*)&ATc[kk][tm * 4];               \
    *(float4*)av[1] = *(const float4*)&ATc[kk][64 + tm * 4];          \
    *(float4*)bv[0] = *(const float4*)&BTc[kk][tn * 4];               \
    *(float4*)bv[1] = *(const float4*)&BTc[kk][64 + tn * 4];          \
    *(float4*)bv[2] = *(const float4*)&BTc[kk][128 + tn * 4];         \
    *(float4*)bv[3] = *(const float4*)&BTc[kk][192 + tn * 4];         \
    _Pragma("unroll") for (int p = 0; p < 2; ++p)                     \
      _Pragma("unroll") for (int q = 0; q < 4; ++q)                   \
        _Pragma("unroll") for (int i = 0; i < 4; ++i)                 \
          _Pragma("unroll") for (int j = 0; j < 4; ++j)               \
            acc[p][q][i][j] = fmaf(av[p][i], bv[q][j], acc[p][q][i][j]); \
  }

#define RAW_BARRIER()                                    \
  asm volatile("s_waitcnt lgkmcnt(0)" ::: "memory");     \
  __builtin_amdgcn_s_barrier();                          \
  asm volatile("" ::: "memory");

// conv: y[b][o][n] = sum_k w[o][k]*relu(bn(hin[b][k][n])) + bias[o]
template <int K, int CO>
__global__ __launch_bounds__(256, 2) void k_convG(
    const float* __restrict__ hin, const float* __restrict__ coef,
    const float* __restrict__ w, const float* __restrict__ bias,
    float* __restrict__ y) {
  __shared__ float At[2][8][132];  // [k][o-128]
  __shared__ float Bt[2][8][264];  // [k][n-256]
  const int n0 = blockIdx.x * 256, o0 = blockIdx.y * 128, b = blockIdx.z;
  const int t = threadIdx.x, tm = t >> 4, tn = t & 15;
  const int wm = t >> 1, wkq = (t & 1) * 4;   // W stage: o-row, k-quad
  const int hr = t >> 5, hc = (t & 31) * 8;   // h stage: k-row, n-col8
  const float* hb = hin + (size_t)b * K * N_SZ + n0;
  float acc[2][4][4][4] = {};
  float4 wreg, hreg0, hreg1;
  float scR, shR;
  wreg = *(const float4*)(w + (size_t)(o0 + wm) * K + wkq);
  hreg0 = *(const float4*)(hb + (size_t)hr * N_SZ + hc);
  hreg1 = *(const float4*)(hb + (size_t)hr * N_SZ + hc + 4);
  scR = coef[hr]; shR = coef[K + hr];
  At[0][wkq + 0][wm] = wreg.x; At[0][wkq + 1][wm] = wreg.y;
  At[0][wkq + 2][wm] = wreg.z; At[0][wkq + 3][wm] = wreg.w;
  {
    float4 u, v2;
    u.x = fmaxf(fmaf(hreg0.x, scR, shR), 0.f);
    u.y = fmaxf(fmaf(hreg0.y, scR, shR), 0.f);
    u.z = fmaxf(fmaf(hreg0.z, scR, shR), 0.f);
    u.w = fmaxf(fmaf(hreg0.w, scR, shR), 0.f);
    v2.x = fmaxf(fmaf(hreg1.x, scR, shR), 0.f);
    v2.y = fmaxf(fmaf(hreg1.y, scR, shR), 0.f);
    v2.z = fmaxf(fmaf(hreg1.z, scR, shR), 0.f);
    v2.w = fmaxf(fmaf(hreg1.w, scR, shR), 0.f);
    *(float4*)&Bt[0][hr][hc] = u;
    *(float4*)&Bt[0][hr][hc + 4] = v2;
  }
  __syncthreads();
  constexpr int NT = K / 8;
#pragma unroll 2
  for (int kt = 0; kt < NT; ++kt) {
    const int cur = kt & 1;
    if (kt + 1 < NT) {
      const int k0 = (kt + 1) * 8;
      wreg = *(const float4*)(w + (size_t)(o0 + wm) * K + k0 + wkq);
      hreg0 = *(const float4*)(hb + (size_t)(k0 + hr) * N_SZ + hc);
      hreg1 = *(const float4*)(hb + (size_t)(k0 + hr) * N_SZ + hc + 4);
      scR = coef[k0 + hr]; shR = coef[K + k0 + hr];
    }
    GEMM_COMPUTE(At[cur], Bt[cur]);
    if (kt + 1 < NT) {
      const int nx = cur ^ 1;
      At[nx][wkq + 0][wm] = wreg.x; At[nx][wkq + 1][wm] = wreg.y;
      At[nx][wkq + 2][wm] = wreg.z; At[nx][wkq + 3][wm] = wreg.w;
      float4 u, v2;
      u.x = fmaxf(fmaf(hreg0.x, scR, shR), 0.f);
      u.y = fmaxf(fmaf(hreg0.y, scR, shR), 0.f);
      u.z = fmaxf(fmaf(hreg0.z, scR, shR), 0.f);
      u.w = fmaxf(fmaf(hreg0.w, scR, shR), 0.f);
      v2.x = fmaxf(fmaf(hreg1.x, scR, shR), 0.f);
      v2.y = fmaxf(fmaf(hreg1.y, scR, shR), 0.f);
      v2.z = fmaxf(fmaf(hreg1.z, scR, shR), 0.f);
      v2.w = fmaxf(fmaf(hreg1.w, scR, shR), 0.f);
      *(float4*)&Bt[nx][hr][hc] = u;
      *(float4*)&Bt[nx][hr][hc + 4] = v2;
      RAW_BARRIER();
    }
  }
#pragma unroll
  for (int p = 0; p < 2; ++p)
#pragma unroll
    for (int i = 0; i < 4; ++i) {
      const int row = o0 + p * 64 + tm * 4 + i;
      const float bvv = bias[row];
      float* yr = y + ((size_t)b * CO + row) * N_SZ + n0;
#pragma unroll
      for (int q = 0; q < 4; ++q) {
        float4 v = {acc[p][q][i][0] + bvv, acc[p][q][i][1] + bvv,
                    acc[p][q][i][2] + bvv, acc[p][q][i][3] + bvv};
        *(float4*)(yr + q * 64 + tn * 4) = v;
      }
    }
}

// uB[b][n][h] = sum_c relu(bn(y3[b][c][n])) * Bm[h][c]
// M = n-rows (128/tile), N = h (256, full H).
__global__ __launch_bounds__(256, 2) void k_uBG(
    const float* __restrict__ y3, const float* __restrict__ coef,
    const float* __restrict__ Bm, float* __restrict__ uB) {
  __shared__ float At[2][8][132];  // [c][n-128]
  __shared__ float Bt[2][8][264];  // [c][h-256]
  const int m0 = blockIdx.x * 128, b = blockIdx.z;
  const int t = threadIdx.x, tm = t >> 4, tn = t & 15;
  const int xr = t >> 5, xc = (t & 31) * 4;  // X stage: c-row, n-col4
  const float* yb = y3 + (size_t)b * C3 * N_SZ + m0;
  float acc[2][4][4][4] = {};
  float4 xreg, breg0, breg1;
  float scR, shR;
  xreg = *(const float4*)(yb + (size_t)xr * N_SZ + xc);
  scR = coef[xr]; shR = coef[C3 + xr];
  breg0 = *(const float4*)(Bm + (size_t)t * H_SZ);
  breg1 = *(const float4*)(Bm + (size_t)t * H_SZ + 4);
  {
    float4 u;
    u.x = fmaxf(fmaf(xreg.x, scR, shR), 0.f);
    u.y = fmaxf(fmaf(xreg.y, scR, shR), 0.f);
    u.z = fmaxf(fmaf(xreg.z, scR, shR), 0.f);
    u.w = fmaxf(fmaf(xreg.w, scR, shR), 0.f);
    *(float4*)&At[0][xr][xc] = u;
    Bt[0][0][t] = breg0.x; Bt[0][1][t] = breg0.y;
    Bt[0][2][t] = breg0.z; Bt[0][3][t] = breg0.w;
    Bt[0][4][t] = breg1.x; Bt[0][5][t] = breg1.y;
    Bt[0][6][t] = breg1.z; Bt[0][7][t] = breg1.w;
  }
  __syncthreads();
  constexpr int NT = C3 / 8;
#pragma unroll 2
  for (int kt = 0; kt < NT; ++kt) {
    const int cur = kt & 1;
    if (kt + 1 < NT) {
      const int c0 = (kt + 1) * 8;
      xreg = *(const float4*)(yb + (size_t)(c0 + xr) * N_SZ + xc);
      scR = coef[c0 + xr]; shR = coef[C3 + c0 + xr];
      breg0 = *(const float4*)(Bm + (size_t)t * H_SZ + c0);
      breg1 = *(const float4*)(Bm + (size_t)t * H_SZ + c0 + 4);
    }
    GEMM_COMPUTE(At[cur], Bt[cur]);
    if (kt + 1 < NT) {
      const int nx = cur ^ 1;
      float4 u;
      u.x = fmaxf(fmaf(xreg.x, scR, shR), 0.f);
      u.y = fmaxf(fmaf(xreg.y, scR, shR), 0.f);
      u.z = fmaxf(fmaf(xreg.z, scR, shR), 0.f);
      u.w = fmaxf(fmaf(xreg.w, scR, shR), 0.f);
      *(float4*)&At[nx][xr][xc] = u;
      Bt[nx][0][t] = breg0.x; Bt[nx][1][t] = breg0.y;
      Bt[nx][2][t] = breg0.z; Bt[nx][3][t] = breg0.w;
      Bt[nx][4][t] = breg1.x; Bt[nx][5][t] = breg1.y;
      Bt[nx][6][t] = breg1.z; Bt[nx][7][t] = breg1.w;
      RAW_BARRIER();
    }
  }
#pragma unroll
  for (int p = 0; p < 2; ++p)
#pragma unroll
    for (int i = 0; i < 4; ++i) {
      const int row = m0 + p * 64 + tm * 4 + i;
      float* orow = uB + ((size_t)b * N_SZ + row) * H_SZ;
#pragma unroll
      for (int q = 0; q < 4; ++q)
        *(float4*)(orow + q * 64 + tn * 4) = *(float4*)acc[p][q][i];
    }
}

// y[b][co][n] = sum_h Cm[co][h] * hs[b][n][h]
__global__ __launch_bounds__(256, 2) void k_ymmG(
    const float* __restrict__ hs, const float* __restrict__ Cm,
    float* __restrict__ y) {
  __shared__ float At[2][8][132];  // [h][co-128]
  __shared__ float Bt[2][8][264];  // [h][n-256]
  const int n0 = blockIdx.x * 256, co0 = blockIdx.y * 128, b = blockIdx.z;
  const int t = threadIdx.x, tm = t >> 4, tn = t & 15;
  const int wm = t >> 1, wkq = (t & 1) * 4;  // Cm stage
  const float* hbase = hs + ((size_t)b * N_SZ + n0) * H_SZ;
  float acc[2][4][4][4] = {};
  float4 creg, hreg0, hreg1;
  creg = *(const float4*)(Cm + (size_t)(co0 + wm) * H_SZ + wkq);
  hreg0 = *(const float4*)(hbase + (size_t)t * H_SZ);
  hreg1 = *(const float4*)(hbase + (size_t)t * H_SZ + 4);
  At[0][wkq + 0][wm] = creg.x; At[0][wkq + 1][wm] = creg.y;
  At[0][wkq + 2][wm] = creg.z; At[0][wkq + 3][wm] = creg.w;
  Bt[0][0][t] = hreg0.x; Bt[0][1][t] = hreg0.y;
  Bt[0][2][t] = hreg0.z; Bt[0][3][t] = hreg0.w;
  Bt[0][4][t] = hreg1.x; Bt[0][5][t] = hreg1.y;
  Bt[0][6][t] = hreg1.z; Bt[0][7][t] = hreg1.w;
  __syncthreads();
  constexpr int NT = H_SZ / 8;
#pragma unroll 2
  for (int kt = 0; kt < NT; ++kt) {
    const int cur = kt & 1;
    if (kt + 1 < NT) {
      const int h0 = (kt + 1) * 8;
      creg = *(const float4*)(Cm + (size_t)(co0 + wm) * H_SZ + h0 + wkq);
      hreg0 = *(const float4*)(hbase + (size_t)t * H_SZ + h0);
      hreg1 = *(const float4*)(hbase + (size_t)t * H_SZ + h0 + 4);
    }
    GEMM_COMPUTE(At[cur], Bt[cur]);
    if (kt + 1 < NT) {
      const int nx = cur ^ 1;
      At[nx][wkq + 0][wm] = creg.x; At[nx][wkq + 1][wm] = creg.y;
      At[nx][wkq + 2][wm] = creg.z; At[nx][wkq + 3][wm] = creg.w;
      Bt[nx][0][t] = hreg0.x; Bt[nx][1][t] = hreg0.y;
      Bt[nx][2][t] = hreg0.z; Bt[nx][3][t] = hreg0.w;
      Bt[nx][4][t] = hreg1.x; Bt[nx][5][t] = hreg1.y;
      Bt[nx][6][t] = hreg1.z; Bt[nx][7][t] = hreg1.w;
      RAW_BARRIER();
    }
  }
#pragma unroll
  for (int p = 0; p < 2; ++p)
#pragma unroll
    for (int i = 0; i < 4; ++i) {
      const int row = co0 + p * 64 + tm * 4 + i;
      float* yr = y + ((size_t)b * C3 + row) * N_SZ + n0;
#pragma unroll
      for (int q = 0; q < 4; ++q)
        *(float4*)(yr + q * 64 + tn * 4) = *(float4*)acc[p][q][i];
    }
}

// ------------------------------------------------------------------
// Scan v5: 64 blocks, 512 threads (8 waves).
// v2's proven b128-broadcast matvec, restructured so that wave wv's
// j-chunk == its output chunk [32wv, 32wv+32):
//  - h_lds is wave-PRIVATE (each wave writes/reads only its chunk)
//  - partials double-buffered in conflict-free [buf][c][i] layout
//  - all 8 waves do the pair-split reduce + DPP combine
//  - ONE lgkm-only barrier per step; u-prefetch/h-store float free.
// ------------------------------------------------------------------
__device__ __forceinline__ float dpp_xor1(float x) {
  int i = __builtin_amdgcn_update_dpp(0, __float_as_int(x), 0xB1, 0xF, 0xF, true);
  return __int_as_float(i);
}

__global__ __launch_bounds__(512, 1) void k_scan(
    const float* __restrict__ A, const float* __restrict__ sinvp,
    const float* __restrict__ uB, float* __restrict__ hs) {
  __shared__ float h_lds[256];
  __shared__ float part[2][8][256];
  const int b = blockIdx.x;
  const int t = threadIdx.x;
  const int lane = t & 63;
  const int wv = t >> 6;
  const float sinv = *sinvp;
  // A panel: rows i = lane + 64k, cols j = 32wv + p
  float a0[32], a1[32], a2[32], a3[32];
  {
    const float* r0 = A + (size_t)(lane) * 256 + wv * 32;
    const float* r1 = A + (size_t)(lane + 64) * 256 + wv * 32;
    const float* r2 = A + (size_t)(lane + 128) * 256 + wv * 32;
    const float* r3 = A + (size_t)(lane + 192) * 256 + wv * 32;
#pragma unroll
    for (int j = 0; j < 32; ++j) {
      a0[j] = r0[j] * sinv; a1[j] = r1[j] * sinv;
      a2[j] = r2[j] * sinv; a3[j] = r3[j] * sinv;
    }
  }
  if (t < 256) h_lds[t] = 0.f;
  __syncthreads();
  const int i_r = wv * 32 + (lane >> 1);  // reduce element (pairs duplicate)
  const int c0 = (lane & 1) * 4;          // which 4 of 8 partials this lane sums
  const float* ub = uB + (size_t)b * N_SZ * H_SZ;
  float* ho = hs + (size_t)b * N_SZ * H_SZ;
  float u_cur = ub[i_r];
  for (int s = 0; s < N_SZ; ++s) {
    float u_next = 0.f;
    if (s + 1 < N_SZ) u_next = ub[(size_t)(s + 1) * H_SZ + i_r];
    // matvec over wave's own chunk: 8 wave-uniform b128 broadcast reads
    const float4* hp = (const float4*)(h_lds + wv * 32);
    float acc0 = 0.f, acc1 = 0.f, acc2 = 0.f, acc3 = 0.f;
#pragma unroll
    for (int q = 0; q < 8; ++q) {
      const float4 h4 = hp[q];
      acc0 = fmaf(a0[q * 4 + 0], h4.x, acc0);
      acc0 = fmaf(a0[q * 4 + 1], h4.y, acc0);
      acc0 = fmaf(a0[q * 4 + 2], h4.z, acc0);
      acc0 = fmaf(a0[q * 4 + 3], h4.w, acc0);
      acc1 = fmaf(a1[q * 4 + 0], h4.x, acc1);
      acc1 = fmaf(a1[q * 4 + 1], h4.y, acc1);
      acc1 = fmaf(a1[q * 4 + 2], h4.z, acc1);
      acc1 = fmaf(a1[q * 4 + 3], h4.w, acc1);
      acc2 = fmaf(a2[q * 4 + 0], h4.x, acc2);
      acc2 = fmaf(a2[q * 4 + 1], h4.y, acc2);
      acc2 = fmaf(a2[q * 4 + 2], h4.z, acc2);
      acc2 = fmaf(a2[q * 4 + 3], h4.w, acc2);
      acc3 = fmaf(a3[q * 4 + 0], h4.x, acc3);
      acc3 = fmaf(a3[q * 4 + 1], h4.y, acc3);
      acc3 = fmaf(a3[q * 4 + 2], h4.z, acc3);
      acc3 = fmaf(a3[q * 4 + 3], h4.w, acc3);
    }
    const int buf = s & 1;
    part[buf][wv][lane] = acc0;
    part[buf][wv][lane + 64] = acc1;
    part[buf][wv][lane + 128] = acc2;
    part[buf][wv][lane + 192] = acc3;
    asm volatile("s_waitcnt lgkmcnt(0)" ::: "memory");
    __builtin_amdgcn_s_barrier();
    asm volatile("" ::: "memory");
    // pair-split reduce: 4 partials each (2-way bank alias = free), DPP pair
    float s0 = part[buf][c0 + 0][i_r];
    float s1 = part[buf][c0 + 1][i_r];
    float s2 = part[buf][c0 + 2][i_r];
    float s3 = part[buf][c0 + 3][i_r];
    float sum = (s0 + s1) + (s2 + s3);
    sum += dpp_xor1(sum);
    float pv = fmaxf(sum + u_cur, 0.f);
    h_lds[i_r] = pv;  // wave-private chunk; pairs write same value
    if ((lane & 1) == 0) ho[(size_t)s * H_SZ + i_r] = pv;
    u_cur = u_next;
    // within-wave RAW on h_lds before next iteration's broadcast reads
    asm volatile("s_waitcnt lgkmcnt(0)" ::: "memory");
  }
}

// ------------------------------------------------------------------
extern "C" void kernel_launch(void* const* d_in, const int* in_sizes, int n_in,
                              void* d_out, int out_size, void* d_ws, size_t ws_size,
                              hipStream_t stream) {
  const float* x   = (const float*)d_in[0];
  const float* w1  = (const float*)d_in[1];
  const float* b1  = (const float*)d_in[2];
  const float* g1  = (const float*)d_in[3];
  const float* be1 = (const float*)d_in[4];
  const float* w2  = (const float*)d_in[5];
  const float* b2  = (const float*)d_in[6];
  const float* g2  = (const float*)d_in[7];
  const float* be2 = (const float*)d_in[8];
  const float* w3  = (const float*)d_in[9];
  const float* b3  = (const float*)d_in[10];
  const float* g3  = (const float*)d_in[11];
  const float* be3 = (const float*)d_in[12];
  const float* A   = (const float*)d_in[13];
  const float* Bm  = (const float*)d_in[14];
  const float* Cm  = (const float*)d_in[15];
  float* out = (float*)d_out;

  char* ws = (char*)d_ws;
  const size_t MB = 1024ull * 1024ull;
  float* y1 = (float*)(ws + 0);          // 16 MB
  float* y2 = (float*)(ws + 16 * MB);    // 32 MB
  float* y3 = (float*)(ws + 48 * MB);    // 64 MB
  float* hs = (float*)(ws + 0);          // 64 MB (y1,y2 dead by scan time)
  char* sp = ws + 112 * MB;
  float* B0 = (float*)(sp);              // 256 KB
  float* P  = (float*)(sp + 256 * 1024);
  float* Q  = (float*)(sp + 512 * 1024);
  float* sinv  = (float*)(sp + 768 * 1024);
  float* coef1 = (float*)(sp + 768 * 1024 + 1024);
  float* coef2 = (float*)(sp + 768 * 1024 + 4096);
  float* coef3 = (float*)(sp + 768 * 1024 + 8192);

  // spectral norm of A
  k_btb<<<256, 256, 0, stream>>>(A, B0);
  {
    float* bufs[2] = {P, Q};
    const float* cur = B0;
    for (int it = 0; it < 12; ++it) {
      float* nxt = bufs[it & 1];
      k_bsq<<<256, 256, 0, stream>>>(cur, nxt);
      cur = nxt;
    }
    k_sfin<<<1, 256, 0, stream>>>(cur, B0, sinv);
  }

  // conv stack
  k_conv1<<<dim3(B_SZ * 4), 256, 0, stream>>>(x, w1, b1, y1);
  k_stats<<<C1, 256, 0, stream>>>(y1, C1, g1, be1, coef1);
  k_convG<C1, C2><<<dim3(4, 1, B_SZ), 256, 0, stream>>>(y1, coef1, w2, b2, y2);
  k_stats<<<C2, 256, 0, stream>>>(y2, C2, g2, be2, coef2);
  k_convG<C2, C3><<<dim3(4, 2, B_SZ), 256, 0, stream>>>(y2, coef2, w3, b3, y3);
  k_stats<<<C3, 256, 0, stream>>>(y3, C3, g3, be3, coef3);

  // uB -> d_out (scratch until final matmul)
  k_uBG<<<dim3(8, 1, B_SZ), 256, 0, stream>>>(y3, coef3, Bm, out);

  // recurrent scan
  k_scan<<<dim3(B_SZ), 512, 0, stream>>>(A, sinv, out, hs);

  // final projection
  k_ymmG<<<dim3(4, 2, B_SZ), 256, 0, stream>>>(hs, Cm, out);
}

// Round 7
// 1109.234 us; speedup vs baseline: 3.8581x; 3.8581x over previous
//
#include <hip/hip_runtime.h>

#define B_SZ 64
#define N_SZ 1024
#define C1   64
#define C2   128
#define C3   256
#define H_SZ 256

// ------------------------------------------------------------------
// Spectral norm of A (256x256) via repeated squaring of B = A^T A.
// ------------------------------------------------------------------
__global__ void k_btb(const float* __restrict__ A, float* __restrict__ B0) {
  int i = blockIdx.x;
  int j = threadIdx.x;
  float acc = 0.f;
  for (int k = 0; k < 256; ++k)
    acc = fmaf(A[k * 256 + i], A[k * 256 + j], acc);
  B0[i * 256 + j] = acc;
}

__global__ void k_bsq(const float* __restrict__ Bin, float* __restrict__ Bout) {
  __shared__ float diag[256];
  int i = blockIdx.x, j = threadIdx.x;
  diag[j] = Bin[j * 256 + j];
  __syncthreads();
  float tr = 0.f;
  for (int k = 0; k < 256; ++k) tr += diag[k];
  float inv = 1.0f / tr;
  float acc = 0.f;
  for (int k = 0; k < 256; ++k)
    acc = fmaf(Bin[i * 256 + k], Bin[k * 256 + j], acc);
  Bout[i * 256 + j] = acc * inv * inv;
}

__global__ void k_sfin(const float* __restrict__ Bf, const float* __restrict__ B0,
                       float* __restrict__ sinv) {
  __shared__ float v[256], w[256];
  __shared__ float red[256];
  __shared__ int redi[256];
  int t = threadIdx.x;
  red[t] = Bf[t * 256 + t];
  redi[t] = t;
  __syncthreads();
  for (int s = 128; s > 0; s >>= 1) {
    if (t < s) {
      if (red[t + s] > red[t]) { red[t] = red[t + s]; redi[t] = redi[t + s]; }
    }
    __syncthreads();
  }
  int jmax = redi[0];
  __syncthreads();
  v[t] = Bf[t * 256 + jmax];
  __syncthreads();
  float acc = 0.f;
  for (int k = 0; k < 256; ++k) acc = fmaf(B0[t * 256 + k], v[k], acc);
  w[t] = acc;
  __syncthreads();
  red[t] = v[t] * w[t];
  __syncthreads();
  for (int s = 128; s > 0; s >>= 1) { if (t < s) red[t] += red[t + s]; __syncthreads(); }
  float num = red[0];
  __syncthreads();
  red[t] = v[t] * v[t];
  __syncthreads();
  for (int s = 128; s > 0; s >>= 1) { if (t < s) red[t] += red[t + s]; __syncthreads(); }
  if (t == 0) {
    float lam = num / red[0];
    float sg = sqrtf(lam);
    *sinv = 1.0f / (sg + 1e-5f);
  }
}

// ------------------------------------------------------------------
// Layer 1: y1 = w1 @ x + b1   (K = 3)
// ------------------------------------------------------------------
__global__ void k_conv1(const float* __restrict__ x, const float* __restrict__ w,
                        const float* __restrict__ bias, float* __restrict__ y) {
  int b = blockIdx.x >> 2;
  int n = ((blockIdx.x & 3) << 8) + threadIdx.x;
  const float* xb = x + (size_t)b * 3 * N_SZ;
  float x0 = xb[n], x1 = xb[N_SZ + n], x2 = xb[2 * N_SZ + n];
  float* yb = y + (size_t)b * C1 * N_SZ;
#pragma unroll 4
  for (int o = 0; o < C1; ++o) {
    float r = fmaf(w[o * 3 + 0], x0,
              fmaf(w[o * 3 + 1], x1,
              fmaf(w[o * 3 + 2], x2, bias[o])));
    yb[(size_t)o * N_SZ + n] = r;
  }
}

// ------------------------------------------------------------------
// Per-channel BN stats over (B, N) -> affine coef.
// ------------------------------------------------------------------
__global__ void k_stats(const float* __restrict__ y, int C,
                        const float* __restrict__ g, const float* __restrict__ be,
                        float* __restrict__ coef) {
  int c = blockIdx.x;
  int t = threadIdx.x;
  float s1 = 0.f, s2 = 0.f;
  for (int b = 0; b < B_SZ; ++b) {
    const float4* p = (const float4*)(y + ((size_t)b * C + c) * N_SZ);
    float4 v = p[t];
    s1 += v.x + v.y + v.z + v.w;
    s2 += v.x * v.x + v.y * v.y + v.z * v.z + v.w * v.w;
  }
  __shared__ float r1[256], r2[256];
  r1[t] = s1; r2[t] = s2;
  __syncthreads();
  for (int s = 128; s > 0; s >>= 1) {
    if (t < s) { r1[t] += r1[t + s]; r2[t] += r2[t + s]; }
    __syncthreads();
  }
  if (t == 0) {
    const float M = (float)(B_SZ * N_SZ);
    float mu = r1[0] / M;
    float var = r2[0] / M - mu * mu;
    float sc = g[c] * rsqrtf(var + 1e-5f);
    coef[c] = sc;
    coef[C + c] = be[c] - mu * sc;
  }
}

// ==================================================================
// GEMM kernels v3: 128x128 tile, 256 threads, 8x8/thread as 2x2
// float4 sub-blocks (64 acc VGPRs -- fits, NO SPILL: R6's 8x16 tile
// spilled acc to scratch, 4.5 GB/dispatch HBM traffic).
// LDS double-buffered, register prefetch, ONE raw lgkm-only barrier
// per k-tile (global loads float across it).
// ==================================================================

#define GEMM_COMPUTE8(ATc, BTc)                                      \
  _Pragma("unroll") for (int kk = 0; kk < 8; ++kk) {                 \
    float av[2][4], bv[2][4];                                        \
    *(float4*)av[0] = *(const float4*)&ATc[kk][ty * 4];              \
    *(float4*)av[1] = *(const float4*)&ATc[kk][64 + ty * 4];         \
    *(float4*)bv[0] = *(const float4*)&BTc[kk][tx * 4];              \
    *(float4*)bv[1] = *(const float4*)&BTc[kk][64 + tx * 4];         \
    _Pragma("unroll") for (int p = 0; p < 2; ++p)                    \
      _Pragma("unroll") for (int q = 0; q < 2; ++q)                  \
        _Pragma("unroll") for (int i = 0; i < 4; ++i)                \
          _Pragma("unroll") for (int j = 0; j < 4; ++j)              \
            acc[p][q][i][j] = fmaf(av[p][i], bv[q][j], acc[p][q][i][j]); \
  }

#define RAW_BARRIER()                                    \
  asm volatile("s_waitcnt lgkmcnt(0)" ::: "memory");     \
  __builtin_amdgcn_s_barrier();                          \
  asm volatile("" ::: "memory");

// conv: y[b][o][n] = sum_k w[o][k]*relu(bn(hin[b][k][n])) + bias[o]
template <int K, int CO>
__global__ __launch_bounds__(256, 2) void k_convG(
    const float* __restrict__ hin, const float* __restrict__ coef,
    const float* __restrict__ w, const float* __restrict__ bias,
    float* __restrict__ y) {
  __shared__ float At[2][8][132];  // [k][o]
  __shared__ float Bt[2][8][132];  // [k][n]
  const int n0 = blockIdx.x * 128, o0 = blockIdx.y * 128, b = blockIdx.z;
  const int t = threadIdx.x, tx = t & 15, ty = t >> 4;
  const int wo = t & 127, wk = (t >> 7) * 4;  // W stage: o-row, k-quad
  const int hr = t >> 5, hc = (t & 31) * 4;   // h stage: k-row, n-col4
  const float* hb = hin + (size_t)b * K * N_SZ + n0;
  float acc[2][2][4][4] = {};
  float4 wreg = *(const float4*)(w + (size_t)(o0 + wo) * K + wk);
  float4 hreg = *(const float4*)(hb + (size_t)hr * N_SZ + hc);
  float scR = coef[hr], shR = coef[K + hr];
  At[0][wk + 0][wo] = wreg.x; At[0][wk + 1][wo] = wreg.y;
  At[0][wk + 2][wo] = wreg.z; At[0][wk + 3][wo] = wreg.w;
  {
    float4 u;
    u.x = fmaxf(fmaf(hreg.x, scR, shR), 0.f);
    u.y = fmaxf(fmaf(hreg.y, scR, shR), 0.f);
    u.z = fmaxf(fmaf(hreg.z, scR, shR), 0.f);
    u.w = fmaxf(fmaf(hreg.w, scR, shR), 0.f);
    *(float4*)&Bt[0][hr][hc] = u;
  }
  __syncthreads();
  constexpr int NT = K / 8;
  for (int kt = 0; kt < NT; ++kt) {
    const int cur = kt & 1;
    if (kt + 1 < NT) {
      const int k0 = (kt + 1) * 8;
      wreg = *(const float4*)(w + (size_t)(o0 + wo) * K + k0 + wk);
      hreg = *(const float4*)(hb + (size_t)(k0 + hr) * N_SZ + hc);
      scR = coef[k0 + hr]; shR = coef[K + k0 + hr];
    }
    GEMM_COMPUTE8(At[cur], Bt[cur]);
    if (kt + 1 < NT) {
      const int nx = cur ^ 1;
      At[nx][wk + 0][wo] = wreg.x; At[nx][wk + 1][wo] = wreg.y;
      At[nx][wk + 2][wo] = wreg.z; At[nx][wk + 3][wo] = wreg.w;
      float4 u;
      u.x = fmaxf(fmaf(hreg.x, scR, shR), 0.f);
      u.y = fmaxf(fmaf(hreg.y, scR, shR), 0.f);
      u.z = fmaxf(fmaf(hreg.z, scR, shR), 0.f);
      u.w = fmaxf(fmaf(hreg.w, scR, shR), 0.f);
      *(float4*)&Bt[nx][hr][hc] = u;
      RAW_BARRIER();
    }
  }
#pragma unroll
  for (int p = 0; p < 2; ++p)
#pragma unroll
    for (int i = 0; i < 4; ++i) {
      const int row = o0 + p * 64 + ty * 4 + i;
      const float bvv = bias[row];
      float* yr = y + ((size_t)b * CO + row) * N_SZ + n0;
      float4 v0 = {acc[p][0][i][0] + bvv, acc[p][0][i][1] + bvv,
                   acc[p][0][i][2] + bvv, acc[p][0][i][3] + bvv};
      float4 v1 = {acc[p][1][i][0] + bvv, acc[p][1][i][1] + bvv,
                   acc[p][1][i][2] + bvv, acc[p][1][i][3] + bvv};
      *(float4*)(yr + tx * 4) = v0;
      *(float4*)(yr + 64 + tx * 4) = v1;
    }
}

// uB[b][n][h] = sum_c relu(bn(y3[b][c][n])) * Bm[h][c]
// rows(ty)=n, cols(tx)=h.
__global__ __launch_bounds__(256, 2) void k_uBG(
    const float* __restrict__ y3, const float* __restrict__ coef,
    const float* __restrict__ Bm, float* __restrict__ uB) {
  __shared__ float Xt[2][8][132];  // [c][n]
  __shared__ float Bt[2][8][132];  // [c][h]
  const int n0 = blockIdx.x * 128, h0 = blockIdx.y * 128, b = blockIdx.z;
  const int t = threadIdx.x, tx = t & 15, ty = t >> 4;
  const int xr = t >> 5, xc = (t & 31) * 4;   // X stage: c-row, n-col4
  const int bh = t & 127, bk = (t >> 7) * 4;  // Bm stage: h-row, c-quad
  const float* yb = y3 + (size_t)b * C3 * N_SZ + n0;
  float acc[2][2][4][4] = {};
  float4 xreg = *(const float4*)(yb + (size_t)xr * N_SZ + xc);
  float scR = coef[xr], shR = coef[C3 + xr];
  float4 breg = *(const float4*)(Bm + (size_t)(h0 + bh) * C3 + bk);
  {
    float4 u;
    u.x = fmaxf(fmaf(xreg.x, scR, shR), 0.f);
    u.y = fmaxf(fmaf(xreg.y, scR, shR), 0.f);
    u.z = fmaxf(fmaf(xreg.z, scR, shR), 0.f);
    u.w = fmaxf(fmaf(xreg.w, scR, shR), 0.f);
    *(float4*)&Xt[0][xr][xc] = u;
    Bt[0][bk + 0][bh] = breg.x; Bt[0][bk + 1][bh] = breg.y;
    Bt[0][bk + 2][bh] = breg.z; Bt[0][bk + 3][bh] = breg.w;
  }
  __syncthreads();
  constexpr int NT = C3 / 8;
  for (int kt = 0; kt < NT; ++kt) {
    const int cur = kt & 1;
    if (kt + 1 < NT) {
      const int c0 = (kt + 1) * 8;
      xreg = *(const float4*)(yb + (size_t)(c0 + xr) * N_SZ + xc);
      scR = coef[c0 + xr]; shR = coef[C3 + c0 + xr];
      breg = *(const float4*)(Bm + (size_t)(h0 + bh) * C3 + c0 + bk);
    }
    GEMM_COMPUTE8(Xt[cur], Bt[cur]);
    if (kt + 1 < NT) {
      const int nx = cur ^ 1;
      float4 u;
      u.x = fmaxf(fmaf(xreg.x, scR, shR), 0.f);
      u.y = fmaxf(fmaf(xreg.y, scR, shR), 0.f);
      u.z = fmaxf(fmaf(xreg.z, scR, shR), 0.f);
      u.w = fmaxf(fmaf(xreg.w, scR, shR), 0.f);
      *(float4*)&Xt[nx][xr][xc] = u;
      Bt[nx][bk + 0][bh] = breg.x; Bt[nx][bk + 1][bh] = breg.y;
      Bt[nx][bk + 2][bh] = breg.z; Bt[nx][bk + 3][bh] = breg.w;
      RAW_BARRIER();
    }
  }
#pragma unroll
  for (int p = 0; p < 2; ++p)
#pragma unroll
    for (int i = 0; i < 4; ++i) {
      const int nrow = n0 + p * 64 + ty * 4 + i;
      float* orow = uB + ((size_t)b * N_SZ + nrow) * H_SZ + h0;
      *(float4*)(orow + tx * 4) = *(float4*)acc[p][0][i];
      *(float4*)(orow + 64 + tx * 4) = *(float4*)acc[p][1][i];
    }
}

// y[b][co][n] = sum_h Cm[co][h] * hs[b][n][h]
// rows(ty)=co, cols(tx)=n.
__global__ __launch_bounds__(256, 2) void k_ymmG(
    const float* __restrict__ hs, const float* __restrict__ Cm,
    float* __restrict__ y) {
  __shared__ float Ct[2][8][132];  // [h][co]
  __shared__ float Ht[2][8][132];  // [h][n]
  const int n0 = blockIdx.x * 128, co0 = blockIdx.y * 128, b = blockIdx.z;
  const int t = threadIdx.x, tx = t & 15, ty = t >> 4;
  const int cc = t & 127, ck = (t >> 7) * 4;  // Cm stage: co-row, h-quad
  const float* hbase = hs + ((size_t)b * N_SZ + n0) * H_SZ;
  float acc[2][2][4][4] = {};
  float4 creg = *(const float4*)(Cm + (size_t)(co0 + cc) * H_SZ + ck);
  float4 hreg = *(const float4*)(hbase + (size_t)cc * H_SZ + ck);
  Ct[0][ck + 0][cc] = creg.x; Ct[0][ck + 1][cc] = creg.y;
  Ct[0][ck + 2][cc] = creg.z; Ct[0][ck + 3][cc] = creg.w;
  Ht[0][ck + 0][cc] = hreg.x; Ht[0][ck + 1][cc] = hreg.y;
  Ht[0][ck + 2][cc] = hreg.z; Ht[0][ck + 3][cc] = hreg.w;
  __syncthreads();
  constexpr int NT = H_SZ / 8;
  for (int kt = 0; kt < NT; ++kt) {
    const int cur = kt & 1;
    if (kt + 1 < NT) {
      const int h0 = (kt + 1) * 8;
      creg = *(const float4*)(Cm + (size_t)(co0 + cc) * H_SZ + h0 + ck);
      hreg = *(const float4*)(hbase + (size_t)cc * H_SZ + h0 + ck);
    }
    GEMM_COMPUTE8(Ct[cur], Ht[cur]);
    if (kt + 1 < NT) {
      const int nx = cur ^ 1;
      Ct[nx][ck + 0][cc] = creg.x; Ct[nx][ck + 1][cc] = creg.y;
      Ct[nx][ck + 2][cc] = creg.z; Ct[nx][ck + 3][cc] = creg.w;
      Ht[nx][ck + 0][cc] = hreg.x; Ht[nx][ck + 1][cc] = hreg.y;
      Ht[nx][ck + 2][cc] = hreg.z; Ht[nx][ck + 3][cc] = hreg.w;
      RAW_BARRIER();
    }
  }
#pragma unroll
  for (int p = 0; p < 2; ++p)
#pragma unroll
    for (int i = 0; i < 4; ++i) {
      const int row = co0 + p * 64 + ty * 4 + i;
      float* yr = y + ((size_t)b * C3 + row) * N_SZ + n0;
      *(float4*)(yr + tx * 4) = *(float4*)acc[p][0][i];
      *(float4*)(yr + 64 + tx * 4) = *(float4*)acc[p][1][i];
    }
}

// ------------------------------------------------------------------
// Scan v5 (unchanged from R6): 64 blocks, 512 threads (8 waves).
// Wave-private h chunk, dbuf conflict-free partials, all-wave pair
// reduce + DPP, ONE lgkm-only barrier per step.
// ------------------------------------------------------------------
__device__ __forceinline__ float dpp_xor1(float x) {
  int i = __builtin_amdgcn_update_dpp(0, __float_as_int(x), 0xB1, 0xF, 0xF, true);
  return __int_as_float(i);
}

__global__ __launch_bounds__(512, 1) void k_scan(
    const float* __restrict__ A, const float* __restrict__ sinvp,
    const float* __restrict__ uB, float* __restrict__ hs) {
  __shared__ float h_lds[256];
  __shared__ float part[2][8][256];
  const int b = blockIdx.x;
  const int t = threadIdx.x;
  const int lane = t & 63;
  const int wv = t >> 6;
  const float sinv = *sinvp;
  float a0[32], a1[32], a2[32], a3[32];
  {
    const float* r0 = A + (size_t)(lane) * 256 + wv * 32;
    const float* r1 = A + (size_t)(lane + 64) * 256 + wv * 32;
    const float* r2 = A + (size_t)(lane + 128) * 256 + wv * 32;
    const float* r3 = A + (size_t)(lane + 192) * 256 + wv * 32;
#pragma unroll
    for (int j = 0; j < 32; ++j) {
      a0[j] = r0[j] * sinv; a1[j] = r1[j] * sinv;
      a2[j] = r2[j] * sinv; a3[j] = r3[j] * sinv;
    }
  }
  if (t < 256) h_lds[t] = 0.f;
  __syncthreads();
  const int i_r = wv * 32 + (lane >> 1);
  const int c0 = (lane & 1) * 4;
  const float* ub = uB + (size_t)b * N_SZ * H_SZ;
  float* ho = hs + (size_t)b * N_SZ * H_SZ;
  float u_cur = ub[i_r];
  for (int s = 0; s < N_SZ; ++s) {
    float u_next = 0.f;
    if (s + 1 < N_SZ) u_next = ub[(size_t)(s + 1) * H_SZ + i_r];
    const float4* hp = (const float4*)(h_lds + wv * 32);
    float acc0 = 0.f, acc1 = 0.f, acc2 = 0.f, acc3 = 0.f;
#pragma unroll
    for (int q = 0; q < 8; ++q) {
      const float4 h4 = hp[q];
      acc0 = fmaf(a0[q * 4 + 0], h4.x, acc0);
      acc0 = fmaf(a0[q * 4 + 1], h4.y, acc0);
      acc0 = fmaf(a0[q * 4 + 2], h4.z, acc0);
      acc0 = fmaf(a0[q * 4 + 3], h4.w, acc0);
      acc1 = fmaf(a1[q * 4 + 0], h4.x, acc1);
      acc1 = fmaf(a1[q * 4 + 1], h4.y, acc1);
      acc1 = fmaf(a1[q * 4 + 2], h4.z, acc1);
      acc1 = fmaf(a1[q * 4 + 3], h4.w, acc1);
      acc2 = fmaf(a2[q * 4 + 0], h4.x, acc2);
      acc2 = fmaf(a2[q * 4 + 1], h4.y, acc2);
      acc2 = fmaf(a2[q * 4 + 2], h4.z, acc2);
      acc2 = fmaf(a2[q * 4 + 3], h4.w, acc2);
      acc3 = fmaf(a3[q * 4 + 0], h4.x, acc3);
      acc3 = fmaf(a3[q * 4 + 1], h4.y, acc3);
      acc3 = fmaf(a3[q * 4 + 2], h4.z, acc3);
      acc3 = fmaf(a3[q * 4 + 3], h4.w, acc3);
    }
    const int buf = s & 1;
    part[buf][wv][lane] = acc0;
    part[buf][wv][lane + 64] = acc1;
    part[buf][wv][lane + 128] = acc2;
    part[buf][wv][lane + 192] = acc3;
    asm volatile("s_waitcnt lgkmcnt(0)" ::: "memory");
    __builtin_amdgcn_s_barrier();
    asm volatile("" ::: "memory");
    float s0 = part[buf][c0 + 0][i_r];
    float s1 = part[buf][c0 + 1][i_r];
    float s2 = part[buf][c0 + 2][i_r];
    float s3 = part[buf][c0 + 3][i_r];
    float sum = (s0 + s1) + (s2 + s3);
    sum += dpp_xor1(sum);
    float pv = fmaxf(sum + u_cur, 0.f);
    h_lds[i_r] = pv;
    if ((lane & 1) == 0) ho[(size_t)s * H_SZ + i_r] = pv;
    u_cur = u_next;
    asm volatile("s_waitcnt lgkmcnt(0)" ::: "memory");
  }
}

// ------------------------------------------------------------------
extern "C" void kernel_launch(void* const* d_in, const int* in_sizes, int n_in,
                              void* d_out, int out_size, void* d_ws, size_t ws_size,
                              hipStream_t stream) {
  const float* x   = (const float*)d_in[0];
  const float* w1  = (const float*)d_in[1];
  const float* b1  = (const float*)d_in[2];
  const float* g1  = (const float*)d_in[3];
  const float* be1 = (const float*)d_in[4];
  const float* w2  = (const float*)d_in[5];
  const float* b2  = (const float*)d_in[6];
  const float* g2  = (const float*)d_in[7];
  const float* be2 = (const float*)d_in[8];
  const float* w3  = (const float*)d_in[9];
  const float* b3  = (const float*)d_in[10];
  const float* g3  = (const float*)d_in[11];
  const float* be3 = (const float*)d_in[12];
  const float* A   = (const float*)d_in[13];
  const float* Bm  = (const float*)d_in[14];
  const float* Cm  = (const float*)d_in[15];
  float* out = (float*)d_out;

  char* ws = (char*)d_ws;
  const size_t MB = 1024ull * 1024ull;
  float* y1 = (float*)(ws + 0);          // 16 MB
  float* y2 = (float*)(ws + 16 * MB);    // 32 MB
  float* y3 = (float*)(ws + 48 * MB);    // 64 MB
  float* hs = (float*)(ws + 0);          // 64 MB (y1,y2 dead by scan time)
  char* sp = ws + 112 * MB;
  float* B0 = (float*)(sp);              // 256 KB
  float* P  = (float*)(sp + 256 * 1024);
  float* Q  = (float*)(sp + 512 * 1024);
  float* sinv  = (float*)(sp + 768 * 1024);
  float* coef1 = (float*)(sp + 768 * 1024 + 1024);
  float* coef2 = (float*)(sp + 768 * 1024 + 4096);
  float* coef3 = (float*)(sp + 768 * 1024 + 8192);

  // spectral norm of A
  k_btb<<<256, 256, 0, stream>>>(A, B0);
  {
    float* bufs[2] = {P, Q};
    const float* cur = B0;
    for (int it = 0; it < 12; ++it) {
      float* nxt = bufs[it & 1];
      k_bsq<<<256, 256, 0, stream>>>(cur, nxt);
      cur = nxt;
    }
    k_sfin<<<1, 256, 0, stream>>>(cur, B0, sinv);
  }

  // conv stack
  k_conv1<<<dim3(B_SZ * 4), 256, 0, stream>>>(x, w1, b1, y1);
  k_stats<<<C1, 256, 0, stream>>>(y1, C1, g1, be1, coef1);
  k_convG<C1, C2><<<dim3(8, 1, B_SZ), 256, 0, stream>>>(y1, coef1, w2, b2, y2);
  k_stats<<<C2, 256, 0, stream>>>(y2, C2, g2, be2, coef2);
  k_convG<C2, C3><<<dim3(8, 2, B_SZ), 256, 0, stream>>>(y2, coef2, w3, b3, y3);
  k_stats<<<C3, 256, 0, stream>>>(y3, C3, g3, be3, coef3);

  // uB -> d_out (scratch until final matmul)
  k_uBG<<<dim3(8, 2, B_SZ), 256, 0, stream>>>(y3, coef3, Bm, out);

  // recurrent scan
  k_scan<<<dim3(B_SZ), 512, 0, stream>>>(A, sinv, out, hs);

  // final projection
  k_ymmG<<<dim3(8, 2, B_SZ), 256, 0, stream>>>(hs, Cm, out);
}